// Round 2
// baseline (134.709 us; speedup 1.0000x reference)
//
#include <hip/hip_runtime.h>

#define IMG_W 512
#define IMG_H 512
#define PLANE_PX (IMG_W * IMG_H)
#define N_ELEMS (48 * PLANE_PX)
#define NTHREADS 256
#define TILEW 48
#define NCT 11                  // 10 full col-tiles + 1 partial (32 cols)
#define NBANDS 8                // 64-row bands
#define NBLK (48 * NBANDS * NCT)   // 4224

// 2*C1 and 2*C2 (the 0.25 scale factors cancel in num/den)
#define C1x2 2.0e-4f
#define C2x2 1.8e-3f

typedef _Float16 h2 __attribute__((ext_vector_type(2)));
typedef _Float16 h8 __attribute__((ext_vector_type(8)));
typedef float f32x4 __attribute__((ext_vector_type(4)));
typedef __fp16 fp16v2 __attribute__((ext_vector_type(2)));

__device__ __forceinline__ unsigned int h2bits(h2 v) {
    union { h2 h; unsigned int u; } c; c.h = v; return c.u;
}
// v_cvt_pkrtz_f16_f32 returns __fp16x2; bit-cast to _Float16x2 (same layout).
__device__ __forceinline__ h2 pkrtz(float x, float y) {
    union { fp16v2 f; h2 h; } c;
    c.f = __builtin_amdgcn_cvt_pkrtz(x, y);
    return c.h;
}

__global__ void __launch_bounds__(NTHREADS, 5) ssim_main(
    const float* __restrict__ img1, const float* __restrict__ img2,
    float* __restrict__ partials)
{
    // 4 separate f16 planes (S, D, SS, DD), each [64 rows][64 staged cols].
    // Plane stride 4096 shorts = 8192 B (folds into ds offset immediates).
    // Col index XOR-swizzled: physical = logical ^ ((row&7)<<3). This keeps
    // 8-f16 (16B) groups contiguous for ds_read_b128 and 4-f16 (8B) groups
    // contiguous for ds_write_b64; both patterns are perfectly bank-balanced.
    __shared__ __align__(16) unsigned short P[4 * 64 * 64];   // 32 KiB -> 5 blk/CU

    const int tid = threadIdx.x;
    const int lane = tid & 63;
    const int wv = tid >> 6;            // wave: Phase A out-row tile / Phase B row set
    const int nr = lane & 15;
    const int khi = lane >> 4;

    // Work decode + XCD swizzle: XCD (blockIdx&7) owns 6 contiguous planes.
    const int xcd = blockIdx.x & 7;
    const int idx = blockIdx.x >> 3;             // [0,528)
    const int pl = xcd * 6 + idx / 88;
    const int t = idx % 88;
    const int band = t / 11;                     // y-band [0,8), 64 rows each
    const int ct = t - band * 11;                // col-tile [0,11)
    const int tx0 = ct * TILEW;
    const int ty0 = band * 64;
    const float* pa = img1 + (size_t)pl * PLANE_PX;
    const float* pb = img2 + (size_t)pl * PLANE_PX;

    // Gaussian band fragment, shared by BOTH convs:
    //   as A (horizontal): A[m][k] = G[k-m], m = lane&15, k = khi*8+j
    //   as B (vertical):   B[k][n] = G[k-n], n = lane&15, k = khi*8+j
    // (identical lane layout; out-of-band entries are exactly 0).
    int sidx = min(lane, 10 - lane);             // < 0 for lane > 10
    unsigned gvb = 0u;
    gvb = (sidx == 0) ? 0x1436u : gvb;           // f16 bits of G[0]
    gvb = (sidx == 1) ? 0x1FC8u : gvb;
    gvb = (sidx == 2) ? 0x289Cu : gvb;
    gvb = (sidx == 3) ? 0x2F00u : gvb;
    gvb = (sidx == 4) ? 0x32D1u : gvb;
    gvb = (sidx == 5) ? 0x3442u : gvb;           // f16 bits of G[5]
    union { h8 h; unsigned u[4]; } af;
#pragma unroll
    for (int w = 0; w < 4; ++w) {
        int t0 = khi * 8 + 2 * w - nr;
        unsigned lo = (unsigned)__shfl((int)gvb, t0 & 63, 64);
        unsigned hi = (unsigned)__shfl((int)gvb, (t0 + 1) & 63, 64);
        af.u[w] = (lo & 0xFFFFu) | (hi << 16);
    }

    const f32x4 z = {0.f, 0.f, 0.f, 0.f};

    // ================= Phase A: vertical conv via MFMA ======================
    // Wave wv computes out rows [wv*16, wv*16+16) x all 64 staged cols as
    // 4 col-tiles. mfma(A = signal, B = af):
    //   A[m][k]: m = staged col in tile (lane&15), k = input-row slot
    //            (khi*8+j) -> column-strip loads, 8 rows x 1 col per thread.
    //   D: row r = khi*4+i = staged col (4 consecutive), col c = lane&15
    //            = out row -> one ds_write_b64 per signal.
    // k slots 26..31 have G[k-n] = 0 (k-n >= 11) so their A values are
    // garbage-but-finite (clamped loads) and contribute nothing.
    const int ry0 = ty0 + wv * 16 - 5;
    const int ryb = ry0 + khi * 8;
    const bool fastY = (ry0 >= 0) && (ry0 + 31 < IMG_H);     // wave-uniform
    const bool edge = (ct == 0) || (ct == NCT - 1);          // block-uniform

#pragma unroll
    for (int tc = 0; tc < 4; ++tc) {
        const int gx = tx0 - 5 + tc * 16 + nr;
        const int cgx = min(max(gx, 0), IMG_W - 1);
        float s[8], d[8];
        if (fastY) {
            const float* qa = pa + (size_t)ryb * IMG_W + cgx;
            const float* qb = pb + (size_t)ryb * IMG_W + cgx;
#pragma unroll
            for (int j = 0; j < 8; ++j) {
                float a = qa[j * IMG_W], b = qb[j * IMG_W];
                s[j] = a + b; d[j] = a - b;
            }
        } else {
#pragma unroll
            for (int j = 0; j < 8; ++j) {
                int ry = ryb + j;
                int ryc = min(max(ry, 0), IMG_H - 1);
                float rm = ((unsigned)ry < (unsigned)IMG_H) ? 1.f : 0.f;
                float a = pa[(size_t)ryc * IMG_W + cgx] * rm;
                float b = pb[(size_t)ryc * IMG_W + cgx] * rm;
                s[j] = a + b; d[j] = a - b;
            }
        }
        union { h8 h; h2 p[4]; } FS, FD, FSS, FDD;
#pragma unroll
        for (int w = 0; w < 4; ++w) {
            FS.p[w] = pkrtz(s[2 * w], s[2 * w + 1]);
            FD.p[w] = pkrtz(d[2 * w], d[2 * w + 1]);
        }
        if (edge) {   // zero-pad OOB columns (mask is thread-uniform)
            const _Float16 ml = ((unsigned)gx < (unsigned)IMG_W) ? (_Float16)1.f
                                                                 : (_Float16)0.f;
            const h2 mlv = {ml, ml};
#pragma unroll
            for (int w = 0; w < 4; ++w) { FS.p[w] *= mlv; FD.p[w] *= mlv; }
        }
#pragma unroll
        for (int w = 0; w < 4; ++w) {
            FSS.p[w] = FS.p[w] * FS.p[w];        // v_pk_mul_f16
            FDD.p[w] = FD.p[w] * FD.p[w];
        }
        f32x4 oS  = __builtin_amdgcn_mfma_f32_16x16x32_f16(FS.h,  af.h, z, 0, 0, 0);
        f32x4 oD  = __builtin_amdgcn_mfma_f32_16x16x32_f16(FD.h,  af.h, z, 0, 0, 0);
        f32x4 oSS = __builtin_amdgcn_mfma_f32_16x16x32_f16(FSS.h, af.h, z, 0, 0, 0);
        f32x4 oDD = __builtin_amdgcn_mfma_f32_16x16x32_f16(FDD.h, af.h, z, 0, 0, 0);

        const int prow = wv * 16 + nr;           // out row (plane row)
        const int swc = (tc * 16 + khi * 4) ^ ((nr & 7) << 3);   // prow&7 == nr&7
        unsigned short* q = &P[prow * 64 + swc];
        *(uint2*)(q)         = make_uint2(h2bits(pkrtz(oS[0],  oS[1])),
                                          h2bits(pkrtz(oS[2],  oS[3])));
        *(uint2*)(q + 4096)  = make_uint2(h2bits(pkrtz(oD[0],  oD[1])),
                                          h2bits(pkrtz(oD[2],  oD[3])));
        *(uint2*)(q + 8192)  = make_uint2(h2bits(pkrtz(oSS[0], oSS[1])),
                                          h2bits(pkrtz(oSS[2], oSS[3])));
        *(uint2*)(q + 12288) = make_uint2(h2bits(pkrtz(oDD[0], oDD[1])),
                                          h2bits(pkrtz(oDD[2], oDD[3])));
    }
    __syncthreads();

    // ================= Phase B: horizontal conv via MFMA + SSIM =============
    // mfma(A = af, B = plane): B[k][n]: n = row (lane&15), k = staged col
    // (khi*8+j) -> ONE ds_read_b128 per signal (no de-interleave).
    // D: r = khi*4+i = out col, c = lane&15 = row.
    const int row = wv * 16 + nr;
    float local = 0.f;
#pragma unroll
    for (int mg = 0; mg < 3; ++mg) {
        if (tx0 + mg * 16 < IMG_W) {             // partial tile skips mg=2
            const int gi = ((mg * 2 + khi) ^ (nr & 7)) * 8;      // swizzled col
            const unsigned short* base = &P[row * 64 + gi];
            h8 fS  = *(const h8*)(base);
            h8 fD  = *(const h8*)(base + 4096);
            h8 fSS = *(const h8*)(base + 8192);
            h8 fDD = *(const h8*)(base + 12288);
            f32x4 aS  = __builtin_amdgcn_mfma_f32_16x16x32_f16(af.h, fS,  z, 0, 0, 0);
            f32x4 aD  = __builtin_amdgcn_mfma_f32_16x16x32_f16(af.h, fD,  z, 0, 0, 0);
            f32x4 aSS = __builtin_amdgcn_mfma_f32_16x16x32_f16(af.h, fSS, z, 0, 0, 0);
            f32x4 aDD = __builtin_amdgcn_mfma_f32_16x16x32_f16(af.h, fDD, z, 0, 0, 0);

            // num/den share the 0.25 factor -> cancelled; constants are 2*C.
#pragma unroll
            for (int i = 0; i < 4; ++i) {
                float cs = aS[i], cd = aD[i], css = aSS[i], cdd = aDD[i];
                float Pq = cs * cs, Qq = cd * cd;
                float U = Pq - Qq;               // 4*mu1*mu2
                float V = Pq + Qq;               // 2*(mu1^2+mu2^2)
                float num = (U + C1x2) * ((css - cdd) - U + C2x2);
                float den = (V + C1x2) * ((css + cdd) - V + C2x2);
                local += num * __builtin_amdgcn_rcpf(den);
            }
        }
    }

    // ================= Block reduction -> one partial ========================
#pragma unroll
    for (int off = 32; off > 0; off >>= 1) local += __shfl_down(local, off, 64);
    __syncthreads();                             // all P reads done: safe alias
    float* wp = (float*)P;
    if (lane == 0) wp[wv] = local;
    __syncthreads();
    if (tid == 0)
        partials[blockIdx.x] = wp[0] + wp[1] + wp[2] + wp[3];
}

__global__ void ssim_final(const float* __restrict__ partials,
                           float* __restrict__ out)
{
    __shared__ float wp[4];
    const int tid = threadIdx.x;
    const float4* p4 = (const float4*)partials;  // 4224/4 = 1056 float4
    float s = 0.f;
    for (int i = tid; i < NBLK / 4; i += NTHREADS) {
        float4 v = p4[i];
        s += (v.x + v.y) + (v.z + v.w);
    }
#pragma unroll
    for (int off = 32; off > 0; off >>= 1) s += __shfl_down(s, off, 64);
    if ((tid & 63) == 0) wp[tid >> 6] = s;
    __syncthreads();
    if (tid == 0)
        out[0] = 1.0f - (wp[0] + wp[1] + wp[2] + wp[3]) * (1.0f / (float)N_ELEMS);
}

extern "C" void kernel_launch(void* const* d_in, const int* in_sizes, int n_in,
                              void* d_out, int out_size, void* d_ws, size_t ws_size,
                              hipStream_t stream) {
    const float* img1 = (const float*)d_in[0];
    const float* img2 = (const float*)d_in[1];
    float* out = (float*)d_out;
    float* partials = (float*)d_ws;     // NBLK floats = 16.9 KB

    ssim_main<<<NBLK, NTHREADS, 0, stream>>>(img1, img2, partials);
    ssim_final<<<1, NTHREADS, 0, stream>>>(partials, out);
}